// Round 13
// baseline (381.500 us; speedup 1.0000x reference)
//
#include <hip/hip_runtime.h>
#include <hip/hip_bf16.h>
#include <hip/hip_fp16.h>
#include <math.h>

#define NN 50000
#define NE 800000

typedef __attribute__((ext_vector_type(8))) short bf16x8;
typedef __attribute__((ext_vector_type(4))) float f32x4;

__device__ __forceinline__ short f2bf(float f){
  unsigned u = __float_as_uint(f);
  unsigned r = (u + 0x7fffu + ((u >> 16) & 1u)) >> 16;
  return (short)r;
}
__device__ __forceinline__ float bf2f(short s){
  return __uint_as_float(((unsigned)(unsigned short)s) << 16);
}

// ---- fp8 e5m2-style via exact f16 scaling (encode keeps top 8 bits of f16) ----
__device__ __forceinline__ unsigned f2fp8(float f){
  __half h = __float2half(f * 0.00390625f);          // v * 2^-8, RNE
  unsigned hb = (unsigned)__half_as_ushort(h);
  unsigned s = hb >> 15;
  unsigned mag = hb & 0x7fffu;
  mag = mag + 0x3fu + ((mag >> 7) & 1u);             // RNE drop of low 7 bits
  unsigned m8 = mag >> 7;
  if (m8 > 0x7eu) m8 = 0x7eu;
  return (s << 7) | m8;
}
__device__ __forceinline__ void fp8x4_dec(unsigned u, float2& lo, float2& hi){
  unsigned l = ((u & 0x80u) << 8) | ((u & 0x7fu) << 7)
             | ((u & 0x8000u) << 16) | ((u & 0x7f00u) << 15);
  unsigned h = ((u & 0x800000u) >> 8) | ((u & 0x7f0000u) >> 9)
             | (u & 0x80000000u) | ((u & 0x7f000000u) >> 1);
  __half2 hl = *(__half2*)&l;
  __half2 hh = *(__half2*)&h;
  lo = __half22float2(hl);
  hi = __half22float2(hh);
}
// manual decode kept deliberately: its VALU work overlaps gather latency (r6 lesson)
__device__ __forceinline__ float fp8_dot4(unsigned a, unsigned b){
  float2 al, ah, bl, bh;
  fp8x4_dec(a, al, ah); fp8x4_dec(b, bl, bh);
  return al.x*bl.x + al.y*bl.y + ah.x*bh.x + ah.y*bh.y;
}

// ---------------- weight prep (transpose + bf16) + cnt/scal zero + W3P fold ----------------
__global__ __launch_bounds__(256) void prep_k(const float* __restrict__ w1,
    const float* __restrict__ w2, const float* __restrict__ w3, const float* __restrict__ pars,
    const float* __restrict__ b3, const float* __restrict__ lin0w, const float* __restrict__ cw1,
    const float* __restrict__ lin1w,
    short* __restrict__ w1t, short* __restrict__ w2t, short* __restrict__ w3t,
    short* __restrict__ w3pt, float* __restrict__ b3P,
    short* __restrict__ lin0wt, short* __restrict__ cw1t0, short* __restrict__ cw1t1,
    short* __restrict__ lin1wt, int* __restrict__ cnt, float* __restrict__ scal){
  int idx = blockIdx.x*256 + threadIdx.x;
  if (idx < NN) cnt[idx] = 0;
  if (idx < 16) scal[idx] = 0.0f;
  if (idx < 65536){
    int n = idx >> 7, k = idx & 127;
    w1t[idx] = f2bf(w1[k*512 + n]);
  } else if (idx < 98304){
    int i = idx - 65536; int n = i >> 9, k = i & 511;
    w2t[i] = f2bf(w2[k*64 + n]);
  } else if (idx < 102400){
    int i = idx - 98304; int n = i >> 6, k = i & 63;
    w3t[i] = f2bf(w3[k*64 + n]);
  } else if (idx < 106496){
    int i = idx - 102400; int c = i >> 6, k = i & 63;
    float s = 0.f;
    for (int j = 0; j < 64; j++)
      s += w3[k*64 + j] * fmaxf(2.f*pars[j*64 + c], 0.f);
    w3pt[i] = f2bf(s);
  } else if (idx < 122880){
    int i = idx - 106496; int n = i >> 7, k = i & 127;
    lin0wt[i] = f2bf(lin0w[k*128 + n]);
  } else if (idx < 139264){
    int i = idx - 122880; int n = i >> 7, k = i & 127;
    cw1t0[i] = f2bf(cw1[k*128 + n]);
  } else if (idx < 155648){
    int i = idx - 139264; int n = i >> 7, k = i & 127;
    cw1t1[i] = f2bf(cw1[16384 + k*128 + n]);
  } else if (idx < 163840){
    int i = idx - 155648; int n = i >> 7, k = i & 127;   // n in [0,64)
    lin1wt[i] = f2bf(lin1w[k*64 + n]);
  } else if (idx < 163904){
    int c = idx - 163840;
    float s = 0.f;
    for (int j = 0; j < 64; j++) s += b3[j] * fmaxf(2.f*pars[j*64 + c], 0.f);
    b3P[c] = s;
  }
}

// ---------------- fused bf16-MFMA MLP chain (64 rows/block, half-split, pad-4) ----------------
__global__ __launch_bounds__(256) void mlp_mfma_k(
    const float* __restrict__ x,
    const short* __restrict__ w1t, const float* __restrict__ b1,
    const short* __restrict__ w2t, const float* __restrict__ b2,
    const short* __restrict__ w3t, const float* __restrict__ b3,
    const short* __restrict__ w3pt, const float* __restrict__ b3P,
    unsigned char* __restrict__ lg8, unsigned char* __restrict__ lgp8,
    short* __restrict__ xb, int M)
{
  __shared__ short xs [64][132];
  __shared__ short h1s[64][260];  // one 256-col half of h1 (+4 pad)
  __shared__ short h2s[64][68];   // phase2 out; overwritten with logitsP after merged phase
  __shared__ short lgs[64][68];
  const int t = threadIdx.x;
  const int wave = t >> 6, lane = t & 63;
  const int quad = lane >> 4, l16 = lane & 15;
  const int m0 = blockIdx.x * 64;

  // stage x -> LDS (bf16), and dump xb directly from registers (fire-and-forget)
  for (int task = t; task < 1024; task += 256){
    int row = task >> 4, c0 = (task & 15) * 8;
    float4 v0 = make_float4(0,0,0,0), v1 = v0;
    int gm = m0 + row;
    if (gm < M){
      v0 = *(const float4*)(x + (size_t)gm*128 + c0);
      v1 = *(const float4*)(x + (size_t)gm*128 + c0 + 4);
    }
    bf16x8 s;
    s[0]=f2bf(v0.x); s[1]=f2bf(v0.y); s[2]=f2bf(v0.z); s[3]=f2bf(v0.w);
    s[4]=f2bf(v1.x); s[5]=f2bf(v1.y); s[6]=f2bf(v1.z); s[7]=f2bf(v1.w);
    *(bf16x8*)&xs[row][c0] = s;
    if (gm < M) *(bf16x8*)(xb + (size_t)gm*128 + c0) = s;
  }
  __syncthreads();

  // ---- Phases 1+2 interleaved over two K-halves of h1 ----
  f32x4 acc2a[4], acc2b[4];
  #pragma unroll
  for (int mt=0;mt<4;mt++){ acc2a[mt] = (f32x4){0.f,0.f,0.f,0.f}; acc2b[mt] = acc2a[mt]; }
  const int n2 = wave*16 + l16;           // phase-2 output column

  #pragma unroll
  for (int half = 0; half < 2; half++){
    // phase 1 (half): h1[:, half*256 .. +256) = relu(x @ w1 + b1), 64 rows
    {
      f32x4 acc[4][4];
      #pragma unroll
      for (int mt=0;mt<4;mt++)
        #pragma unroll
        for (int nt=0;nt<4;nt++) acc[mt][nt] = (f32x4){0.f,0.f,0.f,0.f};
      #pragma unroll
      for (int k0 = 0; k0 < 128; k0 += 32){
        bf16x8 a0 = *(const bf16x8*)&xs[l16     ][k0 + quad*8];
        bf16x8 a1 = *(const bf16x8*)&xs[16 + l16][k0 + quad*8];
        bf16x8 a2 = *(const bf16x8*)&xs[32 + l16][k0 + quad*8];
        bf16x8 a3 = *(const bf16x8*)&xs[48 + l16][k0 + quad*8];
        #pragma unroll
        for (int nt = 0; nt < 4; nt++){
          int n = half*256 + wave*64 + nt*16 + l16;
          bf16x8 b = *(const bf16x8*)(w1t + (size_t)n*128 + k0 + quad*8);
          acc[0][nt] = __builtin_amdgcn_mfma_f32_16x16x32_bf16(a0, b, acc[0][nt], 0,0,0);
          acc[1][nt] = __builtin_amdgcn_mfma_f32_16x16x32_bf16(a1, b, acc[1][nt], 0,0,0);
          acc[2][nt] = __builtin_amdgcn_mfma_f32_16x16x32_bf16(a2, b, acc[2][nt], 0,0,0);
          acc[3][nt] = __builtin_amdgcn_mfma_f32_16x16x32_bf16(a3, b, acc[3][nt], 0,0,0);
        }
      }
      #pragma unroll
      for (int nt = 0; nt < 4; nt++){
        int n  = half*256 + wave*64 + nt*16 + l16;
        int cl = wave*64 + nt*16 + l16;
        float bb = b1[n];
        #pragma unroll
        for (int mt = 0; mt < 4; mt++){
          #pragma unroll
          for (int r = 0; r < 4; r++){
            int row = mt*16 + quad*4 + r;
            h1s[row][cl] = f2bf(fmaxf(acc[mt][nt][r] + bb, 0.f));
          }
        }
      }
    }
    __syncthreads();

    // phase 2 partial: acc2 += h1(half) @ w2[half K range]; 2 indep accs per m-tile
    #pragma unroll
    for (int k0 = 0; k0 < 128; k0 += 32){
      bf16x8 bA = *(const bf16x8*)(w2t + (size_t)n2*512 + half*256 + k0 + quad*8);
      bf16x8 bB = *(const bf16x8*)(w2t + (size_t)n2*512 + half*256 + 128 + k0 + quad*8);
      #pragma unroll
      for (int mt = 0; mt < 4; mt++){
        bf16x8 aA = *(const bf16x8*)&h1s[mt*16 + l16][k0 + quad*8];
        bf16x8 aB = *(const bf16x8*)&h1s[mt*16 + l16][128 + k0 + quad*8];
        acc2a[mt] = __builtin_amdgcn_mfma_f32_16x16x32_bf16(aA, bA, acc2a[mt], 0,0,0);
        acc2b[mt] = __builtin_amdgcn_mfma_f32_16x16x32_bf16(aB, bB, acc2b[mt], 0,0,0);
      }
    }
    if (half == 0) __syncthreads();   // protect h1s before overwrite
  }

  // h2 = relu(acc2a+acc2b + b2) -> h2s
  {
    float bb = b2[n2];
    #pragma unroll
    for (int mt = 0; mt < 4; mt++)
      #pragma unroll
      for (int r = 0; r < 4; r++)
        h2s[mt*16 + quad*4 + r][n2] = f2bf(fmaxf(acc2a[mt][r] + acc2b[mt][r] + bb, 0.f));
  }
  __syncthreads();

  // ---- Merged Phase 3+4: logits = h2@w3t + b3 ; logitsP = h2@w3pt + b3P ----
  {
    f32x4 accL[4], accP[4];
    #pragma unroll
    for (int mt=0;mt<4;mt++){ accL[mt] = (f32x4){0.f,0.f,0.f,0.f}; accP[mt] = accL[mt]; }
    #pragma unroll
    for (int k0 = 0; k0 < 64; k0 += 32){
      bf16x8 bL = *(const bf16x8*)(w3t  + (size_t)n2*64 + k0 + quad*8);
      bf16x8 bP = *(const bf16x8*)(w3pt + (size_t)n2*64 + k0 + quad*8);
      #pragma unroll
      for (int mt = 0; mt < 4; mt++){
        bf16x8 a = *(const bf16x8*)&h2s[mt*16 + l16][k0 + quad*8];
        accL[mt] = __builtin_amdgcn_mfma_f32_16x16x32_bf16(a, bL, accL[mt], 0,0,0);
        accP[mt] = __builtin_amdgcn_mfma_f32_16x16x32_bf16(a, bP, accP[mt], 0,0,0);
      }
    }
    __syncthreads();   // all h2s reads complete before overwrite
    float bbL = b3[n2], bbP = b3P[n2];
    #pragma unroll
    for (int mt = 0; mt < 4; mt++)
      #pragma unroll
      for (int r = 0; r < 4; r++){
        lgs[mt*16 + quad*4 + r][n2] = f2bf(accL[mt][r] + bbL);
        h2s[mt*16 + quad*4 + r][n2] = f2bf(accP[mt][r] + bbP);
      }
  }
  __syncthreads();

  // ---- cooperative store: lgs -> lg8 (fp8), h2s -> lgp8 (fp8); 16 cols/thread ----
  {
    int row = t >> 2, c0 = (t & 3) * 16;
    int gm = m0 + row;
    if (gm < M){
      const short* pl = &lgs[row][c0];
      const short* pp = &h2s[row][c0];
      unsigned a[4] = {0,0,0,0}, b[4] = {0,0,0,0};
      #pragma unroll
      for (int q2 = 0; q2 < 4; q2++){
        #pragma unroll
        for (int j = 0; j < 4; j++){
          a[q2] |= f2fp8(bf2f(pl[q2*4+j])) << (8*j);
          b[q2] |= f2fp8(bf2f(pp[q2*4+j])) << (8*j);
        }
      }
      uint4 av; av.x=a[0]; av.y=a[1]; av.z=a[2]; av.w=a[3];
      uint4 bv; bv.x=b[0]; bv.y=b[1]; bv.z=b[2]; bv.w=b[3];
      *(uint4*)(lg8  + (size_t)gm*64 + c0) = av;
      *(uint4*)(lgp8 + (size_t)gm*64 + c0) = bv;
    }
  }
}

// ---------------- bf16 MFMA GEMM (x0 only now): C = EPI(A @ Bt^T) ----------------
template<int NT, bool RELU, bool RESID, bool BF16OUT, bool SCALEROW>
__global__ __launch_bounds__(256) void bgemm_k(
    const short* __restrict__ A, const short* __restrict__ Bt,
    const float* __restrict__ bias, const short* __restrict__ extra,
    const float* __restrict__ dinvp,
    float* __restrict__ C, short* __restrict__ Cb, int M, float beta)
{
  const int N = NT*64;
  __shared__ short As[32][132];
  const int t = threadIdx.x;
  const int wave = t >> 6, lane = t & 63;
  const int quad = lane >> 4, l16 = lane & 15;
  const int m0 = blockIdx.x * 32;

  for (int task = t; task < 512; task += 256){
    int row = task >> 4, c0 = (task & 15) * 8;
    bf16x8 v = {0,0,0,0,0,0,0,0};
    if (m0 + row < M) v = *(const bf16x8*)(A + (size_t)(m0+row)*128 + c0);
    *(bf16x8*)&As[row][c0] = v;
  }
  __syncthreads();

  f32x4 acc[2][NT];
  #pragma unroll
  for (int mt=0;mt<2;mt++)
    #pragma unroll
    for (int nt=0;nt<NT;nt++) acc[mt][nt] = (f32x4){0.f,0.f,0.f,0.f};

  #pragma unroll
  for (int k0 = 0; k0 < 128; k0 += 32){
    bf16x8 a0 = *(const bf16x8*)&As[l16     ][k0 + quad*8];
    bf16x8 a1 = *(const bf16x8*)&As[16 + l16][k0 + quad*8];
    #pragma unroll
    for (int nt = 0; nt < NT; nt++){
      int n = (wave*NT + nt)*16 + l16;
      bf16x8 b = *(const bf16x8*)(Bt + (size_t)n*128 + k0 + quad*8);
      acc[0][nt] = __builtin_amdgcn_mfma_f32_16x16x32_bf16(a0, b, acc[0][nt], 0,0,0);
      acc[1][nt] = __builtin_amdgcn_mfma_f32_16x16x32_bf16(a1, b, acc[1][nt], 0,0,0);
    }
  }

  #pragma unroll
  for (int nt = 0; nt < NT; nt++){
    int n = (wave*NT + nt)*16 + l16;
    float bb = (bias != nullptr) ? bias[n] : 0.f;
    #pragma unroll
    for (int mt = 0; mt < 2; mt++){
      #pragma unroll
      for (int r = 0; r < 4; r++){
        int gm = m0 + mt*16 + quad*4 + r;
        if (gm >= M) continue;
        float v = acc[mt][nt][r];
        if (RESID){
          float ex = bf2f(extra[(size_t)gm*N + n]);
          v = beta*v + (1.f - beta)*ex;
        }
        v += bb;
        if (RELU) v = fmaxf(v, 0.f);
        if (SCALEROW) v *= dinvp[gm];
        if (BF16OUT) Cb[(size_t)gm*N + n] = f2bf(v);
        else         C [(size_t)gm*N + n] = v;
      }
    }
  }
}

// ---------------- fused gather-agg (32 nodes/block) + layer GEMM [+ final out GEMM] ----------
// Wave w gathers rows w*8..w*8+8 of the agg tile into As (LDS), then the block runs
// h = relu(beta*(agg@Bt) + (1-beta)*agg) with the residual read FROM LDS.
// LAST=false: h *= dinv (prescale for next gather), -> Cb.  LAST=true: h -> As, out GEMM.
template<bool LAST>
__global__ __launch_bounds__(256) void agg_bgemm_k(
    const short* __restrict__ hb,
    const int* __restrict__ off, const int2* __restrict__ sd, const float* __restrict__ w,
    const float* __restrict__ dinv,
    const short* __restrict__ Bt,
    const short* __restrict__ lin1wt, const float* __restrict__ lin1b,
    short* __restrict__ Cb, float* __restrict__ out, int M, float beta)
{
  __shared__ short As[32][132];
  const int t = threadIdx.x;
  const int wave = t >> 6, lane = t & 63;
  const int quad = lane >> 4, l16 = lane & 15;
  const int m0 = blockIdx.x * 32;

  // ---- gather phase: agg[n] = dinv[n]*(h'[n] + sum w*h'[src]) -> As ----
  for (int rr = 0; rr < 8; rr++){
    int row = wave*8 + rr;
    int n = m0 + row;
    float acc0 = 0.f, acc1 = 0.f;
    if (n < M){
      float d = dinv[n];
      short2 hv = *(const short2*)(hb + (size_t)n*128 + lane*2);
      acc0 = bf2f(hv.x); acc1 = bf2f(hv.y);
      int s = off[n], e = off[n+1];
      int j = s;
      for (; j + 7 < e; j += 8){
        int4 p0 = *(const int4*)(sd + j);
        int4 p1 = *(const int4*)(sd + j + 2);
        int4 p2 = *(const int4*)(sd + j + 4);
        int4 p3 = *(const int4*)(sd + j + 6);
        float4 w0 = *(const float4*)(w + j);
        float4 w1 = *(const float4*)(w + j + 4);
        short2 h0 = *(const short2*)(hb + (size_t)p0.x*128 + lane*2);
        short2 h1 = *(const short2*)(hb + (size_t)p0.z*128 + lane*2);
        short2 h2 = *(const short2*)(hb + (size_t)p1.x*128 + lane*2);
        short2 h3 = *(const short2*)(hb + (size_t)p1.z*128 + lane*2);
        short2 h4 = *(const short2*)(hb + (size_t)p2.x*128 + lane*2);
        short2 h5 = *(const short2*)(hb + (size_t)p2.z*128 + lane*2);
        short2 h6 = *(const short2*)(hb + (size_t)p3.x*128 + lane*2);
        short2 h7 = *(const short2*)(hb + (size_t)p3.z*128 + lane*2);
        acc0 += w0.x*bf2f(h0.x) + w0.y*bf2f(h1.x) + w0.z*bf2f(h2.x) + w0.w*bf2f(h3.x)
              + w1.x*bf2f(h4.x) + w1.y*bf2f(h5.x) + w1.z*bf2f(h6.x) + w1.w*bf2f(h7.x);
        acc1 += w0.x*bf2f(h0.y) + w0.y*bf2f(h1.y) + w0.z*bf2f(h2.y) + w0.w*bf2f(h3.y)
              + w1.x*bf2f(h4.y) + w1.y*bf2f(h5.y) + w1.z*bf2f(h6.y) + w1.w*bf2f(h7.y);
      }
      for (; j < e; j++){
        int2 p = sd[j];
        short2 h0 = *(const short2*)(hb + (size_t)p.x*128 + lane*2);
        float w0 = w[j];
        acc0 += w0*bf2f(h0.x); acc1 += w0*bf2f(h0.y);
      }
      acc0 *= d; acc1 *= d;
    }
    short2 o; o.x = f2bf(acc0); o.y = f2bf(acc1);
    *(short2*)&As[row][lane*2] = o;
  }
  __syncthreads();

  // ---- GEMM: acc = agg @ Bt (N=128) ----
  f32x4 acc[2][2];
  #pragma unroll
  for (int mt=0;mt<2;mt++)
    #pragma unroll
    for (int nt=0;nt<2;nt++) acc[mt][nt] = (f32x4){0.f,0.f,0.f,0.f};
  #pragma unroll
  for (int k0 = 0; k0 < 128; k0 += 32){
    bf16x8 a0 = *(const bf16x8*)&As[l16     ][k0 + quad*8];
    bf16x8 a1 = *(const bf16x8*)&As[16 + l16][k0 + quad*8];
    #pragma unroll
    for (int nt = 0; nt < 2; nt++){
      int n = (wave*2 + nt)*16 + l16;
      bf16x8 b = *(const bf16x8*)(Bt + (size_t)n*128 + k0 + quad*8);
      acc[0][nt] = __builtin_amdgcn_mfma_f32_16x16x32_bf16(a0, b, acc[0][nt], 0,0,0);
      acc[1][nt] = __builtin_amdgcn_mfma_f32_16x16x32_bf16(a1, b, acc[1][nt], 0,0,0);
    }
  }

  if (!LAST){
    // epilogue: h' = relu(beta*acc + (1-beta)*agg) * dinv -> Cb
    #pragma unroll
    for (int nt = 0; nt < 2; nt++){
      int n = (wave*2 + nt)*16 + l16;
      #pragma unroll
      for (int mt = 0; mt < 2; mt++){
        #pragma unroll
        for (int r = 0; r < 4; r++){
          int row = mt*16 + quad*4 + r;
          int gm = m0 + row;
          if (gm >= M) continue;
          float ex = bf2f(As[row][n]);
          float v = fmaxf(beta*acc[mt][nt][r] + (1.f - beta)*ex, 0.f) * dinv[gm];
          Cb[(size_t)gm*128 + n] = f2bf(v);
        }
      }
    }
  } else {
    // epilogue: h = relu(beta*acc + (1-beta)*agg) -> As (after all reads), then out GEMM
    short hloc[2][2][4];
    #pragma unroll
    for (int nt = 0; nt < 2; nt++){
      int n = (wave*2 + nt)*16 + l16;
      #pragma unroll
      for (int mt = 0; mt < 2; mt++)
        #pragma unroll
        for (int r = 0; r < 4; r++){
          int row = mt*16 + quad*4 + r;
          float ex = bf2f(As[row][n]);
          hloc[nt][mt][r] = f2bf(fmaxf(beta*acc[mt][nt][r] + (1.f - beta)*ex, 0.f));
        }
    }
    __syncthreads();
    #pragma unroll
    for (int nt = 0; nt < 2; nt++){
      int n = (wave*2 + nt)*16 + l16;
      #pragma unroll
      for (int mt = 0; mt < 2; mt++)
        #pragma unroll
        for (int r = 0; r < 4; r++)
          As[mt*16 + quad*4 + r][n] = hloc[nt][mt][r];
    }
    __syncthreads();

    f32x4 acc2[2];
    acc2[0] = (f32x4){0.f,0.f,0.f,0.f}; acc2[1] = acc2[0];
    const int n2 = wave*16 + l16;     // 64 output cols
    #pragma unroll
    for (int k0 = 0; k0 < 128; k0 += 32){
      bf16x8 b  = *(const bf16x8*)(lin1wt + (size_t)n2*128 + k0 + quad*8);
      bf16x8 a0 = *(const bf16x8*)&As[l16     ][k0 + quad*8];
      bf16x8 a1 = *(const bf16x8*)&As[16 + l16][k0 + quad*8];
      acc2[0] = __builtin_amdgcn_mfma_f32_16x16x32_bf16(a0, b, acc2[0], 0,0,0);
      acc2[1] = __builtin_amdgcn_mfma_f32_16x16x32_bf16(a1, b, acc2[1], 0,0,0);
    }
    float bb = lin1b[n2];
    #pragma unroll
    for (int mt = 0; mt < 2; mt++)
      #pragma unroll
      for (int r = 0; r < 4; r++){
        int gm = m0 + mt*16 + quad*4 + r;
        if (gm < M) out[(size_t)gm*64 + n2] = acc2[mt][r] + bb;
      }
  }
}

// ---------------- count in-degree + record per-edge rank (4 edges/thread ILP) ----------------
__global__ __launch_bounds__(256) void count_k(const int* __restrict__ col, int* __restrict__ cnt,
    int* __restrict__ rank, int E){
  int i = (blockIdx.x*256 + threadIdx.x)*4;
  if (i + 3 < E){
    int4 c = *(const int4*)(col + i);
    int r0 = atomicAdd(&cnt[c.x], 1);
    int r1 = atomicAdd(&cnt[c.y], 1);
    int r2 = atomicAdd(&cnt[c.z], 1);
    int r3 = atomicAdd(&cnt[c.w], 1);
    *(int4*)(rank + i) = make_int4(r0, r1, r2, r3);
  } else {
    for (; i < E; i++) rank[i] = atomicAdd(&cnt[col[i]], 1);
  }
}

// ---------------- scan: per-block sums, then final (block base summed in-kernel) ----------------
__global__ __launch_bounds__(256) void scan_sums_k(const int* __restrict__ cnt, int* __restrict__ bsum, int n){
  __shared__ int s[256];
  const int t = threadIdx.x;
  int i = blockIdx.x*1024 + t*4;
  int4 v = make_int4(0,0,0,0);
  if (i + 3 < n) v = *(const int4*)(cnt + i);
  else {
    if (i   < n) v.x = cnt[i];
    if (i+1 < n) v.y = cnt[i+1];
    if (i+2 < n) v.z = cnt[i+2];
    if (i+3 < n) v.w = cnt[i+3];
  }
  s[t] = v.x + v.y + v.z + v.w;
  __syncthreads();
  for (int st = 128; st; st >>= 1){
    if (t < st) s[t] += s[t + st];
    __syncthreads();
  }
  if (t == 0) bsum[blockIdx.x] = s[0];
}

__global__ __launch_bounds__(256) void scan_final_k(const int* __restrict__ cnt, const int* __restrict__ bsum,
    int* __restrict__ off, int n, int total, int nb){
  __shared__ int s[256];
  __shared__ int basebs;
  const int t = threadIdx.x;
  if (t < 64){
    int v = (t < nb && t < (int)blockIdx.x) ? bsum[t] : 0;
    #pragma unroll
    for (int o = 1; o < 64; o <<= 1) v += __shfl_xor(v, o);
    if (t == 0) basebs = v;
  }
  int i = blockIdx.x*1024 + t*4;
  int4 v = make_int4(0,0,0,0);
  if (i + 3 < n) v = *(const int4*)(cnt + i);
  else {
    if (i   < n) v.x = cnt[i];
    if (i+1 < n) v.y = cnt[i+1];
    if (i+2 < n) v.z = cnt[i+2];
    if (i+3 < n) v.w = cnt[i+3];
  }
  int tsum = v.x + v.y + v.z + v.w;
  s[t] = tsum;
  __syncthreads();
  #pragma unroll
  for (int st = 1; st < 256; st <<= 1){
    int a = (t >= st) ? s[t - st] : 0;
    __syncthreads();
    s[t] += a;
    __syncthreads();
  }
  int base = s[t] - tsum + basebs;
  int o0 = base, o1 = o0 + v.x, o2 = o1 + v.y, o3 = o2 + v.z;
  if (i   < n) off[i]   = o0;
  if (i+1 < n) off[i+1] = o1;
  if (i+2 < n) off[i+2] = o2;
  if (i+3 < n) off[i+3] = o3;
  if (blockIdx.x == 0 && t == 0) off[n] = total;
}

// bucket edges by destination; slot = off[c] + rank[e] (NO atomic; 4 edges/thread ILP)
__global__ __launch_bounds__(256) void scatter_k(const int* __restrict__ row, const int* __restrict__ col,
    const int* __restrict__ off, const int* __restrict__ rank,
    int2* __restrict__ csr_sd, int E){
  int i = (blockIdx.x*256 + threadIdx.x)*4;
  if (i + 3 < E){
    int4 r = *(const int4*)(row + i);
    int4 c = *(const int4*)(col + i);
    int4 k = *(const int4*)(rank + i);
    int o0 = off[c.x], o1 = off[c.y], o2 = off[c.z], o3 = off[c.w];
    int2 p0; p0.x = r.x; p0.y = c.x;
    int2 p1; p1.x = r.y; p1.y = c.y;
    int2 p2; p2.x = r.z; p2.y = c.z;
    int2 p3; p3.x = r.w; p3.y = c.w;
    csr_sd[o0 + k.x] = p0;
    csr_sd[o1 + k.y] = p1;
    csr_sd[o2 + k.z] = p2;
    csr_sd[o3 + k.w] = p3;
  } else {
    for (; i < E; i++){
      int2 p; p.x = row[i]; p.y = col[i];
      csr_sd[off[col[i]] + rank[i]] = p;
    }
  }
}

// ---------------- ew over CSR slots: 16-lane groups, 8-edge batch pipeline ----------------
__global__ __launch_bounds__(256) void ew2_k(const unsigned char* __restrict__ lg8,
    const unsigned char* __restrict__ lgp8,
    const int2* __restrict__ sd,
    float* __restrict__ w, float* __restrict__ scal, int E){
  const int t = threadIdx.x;
  const int lane = t & 63, wid = t >> 6;
  const int g = lane >> 4, q = lane & 15;
  const int gid = (blockIdx.x*4 + wid)*4 + g;     // global 16-lane group id
  const int ngroups = gridDim.x*16;
  float s = 0.f, ss = 0.f;
  for (int base = gid*8; base < E; base += ngroups*8){   // E % 8 == 0
    int4 p01 = *(const int4*)(sd + base);
    int4 p23 = *(const int4*)(sd + base + 2);
    int4 p45 = *(const int4*)(sd + base + 4);
    int4 p67 = *(const int4*)(sd + base + 6);
    unsigned a0 = *(const unsigned*)(lg8  + (size_t)p01.x*64 + q*4);
    unsigned a1 = *(const unsigned*)(lg8  + (size_t)p01.z*64 + q*4);
    unsigned a2 = *(const unsigned*)(lg8  + (size_t)p23.x*64 + q*4);
    unsigned a3 = *(const unsigned*)(lg8  + (size_t)p23.z*64 + q*4);
    unsigned a4 = *(const unsigned*)(lg8  + (size_t)p45.x*64 + q*4);
    unsigned a5 = *(const unsigned*)(lg8  + (size_t)p45.z*64 + q*4);
    unsigned a6 = *(const unsigned*)(lg8  + (size_t)p67.x*64 + q*4);
    unsigned a7 = *(const unsigned*)(lg8  + (size_t)p67.z*64 + q*4);
    unsigned b0 = *(const unsigned*)(lgp8 + (size_t)p01.y*64 + q*4);
    unsigned b1 = *(const unsigned*)(lgp8 + (size_t)p01.w*64 + q*4);
    unsigned b2 = *(const unsigned*)(lgp8 + (size_t)p23.y*64 + q*4);
    unsigned b3 = *(const unsigned*)(lgp8 + (size_t)p23.w*64 + q*4);
    unsigned b4 = *(const unsigned*)(lgp8 + (size_t)p45.y*64 + q*4);
    unsigned b5 = *(const unsigned*)(lgp8 + (size_t)p45.w*64 + q*4);
    unsigned b6 = *(const unsigned*)(lgp8 + (size_t)p67.y*64 + q*4);
    unsigned b7 = *(const unsigned*)(lgp8 + (size_t)p67.w*64 + q*4);
    float v0 = fp8_dot4(a0, b0);
    float v1 = fp8_dot4(a1, b1);
    float v2 = fp8_dot4(a2, b2);
    float v3 = fp8_dot4(a3, b3);
    float v4 = fp8_dot4(a4, b4);
    float v5 = fp8_dot4(a5, b5);
    float v6 = fp8_dot4(a6, b6);
    float v7 = fp8_dot4(a7, b7);
    #pragma unroll
    for (int o = 1; o < 16; o <<= 1){
      v0 += __shfl_xor(v0, o); v1 += __shfl_xor(v1, o);
      v2 += __shfl_xor(v2, o); v3 += __shfl_xor(v3, o);
      v4 += __shfl_xor(v4, o); v5 += __shfl_xor(v5, o);
      v6 += __shfl_xor(v6, o); v7 += __shfl_xor(v7, o);
    }
    if (q == 0){
      float4 va = make_float4(v0*65536.f, v1*65536.f, v2*65536.f, v3*65536.f);
      float4 vb = make_float4(v4*65536.f, v5*65536.f, v6*65536.f, v7*65536.f);
      *(float4*)(w + base)     = va;
      *(float4*)(w + base + 4) = vb;
      s  += va.x + va.y + va.z + va.w + vb.x + vb.y + vb.z + vb.w;
      ss += va.x*va.x + va.y*va.y + va.z*va.z + va.w*va.w
          + vb.x*vb.x + vb.y*vb.y + vb.z*vb.z + vb.w*vb.w;
    }
  }
  #pragma unroll
  for (int o = 1; o < 64; o <<= 1){ s += __shfl_xor(s, o); ss += __shfl_xor(ss, o); }
  __shared__ float ls[4], lss[4];
  if (lane == 0){ ls[wid] = s; lss[wid] = ss; }
  __syncthreads();
  if (t == 0){
    atomicAdd(&scal[0], ls[0]+ls[1]+ls[2]+ls[3]);
    atomicAdd(&scal[1], lss[0]+lss[1]+lss[2]+lss[3]);
  }
}

// normalize bucket in place (stats inline), deg = 1 + sum(w), dinv = rsqrt(deg)
__global__ __launch_bounds__(256) void degnorm_k(float* __restrict__ w, const int* __restrict__ off,
    const float* __restrict__ scal, float* __restrict__ dinv, int Nn, int E){
  int n = blockIdx.x*256 + threadIdx.x;
  if (n < Nn){
    double sum = (double)scal[0], sumsq = (double)scal[1];
    double mean_d = sum / (double)E;
    double var    = (sumsq - sum*sum/(double)E) / (double)(E-1);
    float mean = (float)mean_d;
    float k    = (float)sqrt(1e-4 / var);
    int s = off[n], e = off[n+1];
    float d = 1.0f;
    for (int j = s; j < e; j++){
      float v = (w[j] - mean) * k + 1.0f;
      w[j] = v;
      d += v;
    }
    dinv[n] = (d > 0.f) ? rsqrtf(d) : 0.f;
  }
}

extern "C" void kernel_launch(void* const* d_in, const int* in_sizes, int n_in,
                              void* d_out, int out_size, void* d_ws, size_t ws_size,
                              hipStream_t stream){
  const float* x      = (const float*)d_in[0];
  const int*   ei     = (const int*)  d_in[1];
  const float* w1     = (const float*)d_in[2];
  const float* b1     = (const float*)d_in[3];
  const float* w2     = (const float*)d_in[4];
  const float* b2     = (const float*)d_in[5];
  const float* w3     = (const float*)d_in[6];
  const float* b3     = (const float*)d_in[7];
  const float* pars   = (const float*)d_in[8];
  const float* lin0w  = (const float*)d_in[9];
  const float* lin0b  = (const float*)d_in[10];
  const float* lin1w  = (const float*)d_in[11];
  const float* lin1b  = (const float*)d_in[12];
  const float* cw1    = (const float*)d_in[13];
  float* out          = (float*)d_out;

  float* ws = (float*)d_ws;
  // workspace layout (float-element offsets)
  int*   cnt     = (int*)(ws + 0);            //    50,000
  int*   off     = (int*)(ws + 50048);        //    50,001
  int2*  csr_sd  = (int2*)(ws + 150144);      //   800,000 int2 (1.6M ints, ends 1,750,144)
  int*   bsum    = (int*)(ws + 1750400);      //        64
  short* lin0wt  = (short*)(ws + 1751000);    //  16,384 shorts
  short* cw1t0   = lin0wt + 16384;            //  16,384
  short* cw1t1   = cw1t0 + 16384;             //  16,384
  short* lin1wt  = cw1t1 + 16384;             //   8,192
  unsigned char* lg8  = (unsigned char*)(ws + 1800000);  // 3.2M bytes (fp8 logits)
  unsigned char* lgp8 = (unsigned char*)(ws + 2600000);  // 3.2M bytes (fp8 logitsP)
  float* csr_w2  = ws + 3400000;              //   800,000 floats (raw ew -> normalized)
  float* dinv    = ws + 5800000;              //    50,000
  float* scal    = ws + 5850048;              //        16 (ends 5850064)
  float* b3P     = ws + 5850064;              //        64 (ends 5850128)
  short* bufAb   = (short*)(ws + 5900000);    // 6.4M shorts (x0 * dinv)
  short* bufCb   = (short*)(ws + 9100000);    // 6.4M shorts (h after layer0 * dinv)
  short* w1t     = (short*)(ws + 18700000);   // 106,496 shorts MLP weights
  short* w2t     = w1t + 65536;
  short* w3t     = w2t + 32768;
  short* w3pt    = w3t + 4096;                // 4,096 shorts (W3P = w3 @ relu(2P))
  short* xb      = (short*)(ws + 18800000);   // 6.4M shorts (bf16 x, ends 22,000,000)
  int*   rank    = (int*)(ws + 22000000);     //   800,000 ints (ends 22,800,000)

  const int Mn = NN, E = NE;
  const int* erow = ei;
  const int* ecol = ei + E;
  const float beta0 = 0.69314718055994530942f;  // ln(2)
  const float beta1 = 0.40546510810816438198f;  // ln(1.5)
  const int nScanB = (Mn + 1023) / 1024;        // 49 <= 64
  const int nGB = (Mn + 31) / 32;               // bgemm grid
  const int nE4 = (E/4 + 255) / 256;            // 4-edges-per-thread grids

  // 1) weight prep + cnt/scal zero + W3P/b3P fold (fused)
  prep_k<<<(163904+255)/256, 256, 0, stream>>>(w1, w2, w3, pars, b3, lin0w, cw1, lin1w,
                                               w1t, w2t, w3t, w3pt, b3P,
                                               lin0wt, cw1t0, cw1t1, lin1wt, cnt, scal);
  // 2) CSR structure: count (records rank) + scan (2 kernels) + atomic-free scatter
  count_k<<<nE4, 256, 0, stream>>>(ecol, cnt, rank, E);
  scan_sums_k<<<nScanB, 256, 0, stream>>>(cnt, bsum, Mn);
  scan_final_k<<<nScanB, 256, 0, stream>>>(cnt, bsum, off, Mn, E, nScanB);
  scatter_k<<<nE4, 256, 0, stream>>>(erow, ecol, off, rank, csr_sd, E);
  // 3) fused bf16-MFMA MLP chain (merged P3/P4 via W3P) -> lg8, lgp8 + xb
  mlp_mfma_k<<<(Mn+63)/64, 256, 0, stream>>>(x, w1t, b1, w2t, b2, w3t, b3, w3pt, b3P,
                                             lg8, lgp8, xb, Mn);
  // 4) ew (manual decode, 8-edge batch, 1024 blocks) + stats; degnorm -> w + dinv
  ew2_k<<<1024, 256, 0, stream>>>(lg8, lgp8, csr_sd, csr_w2, scal, E);
  degnorm_k<<<(Mn+255)/256, 256, 0, stream>>>(csr_w2, off, scal, dinv, Mn, E);
  // 5) x0' = relu(xb@lin0wt + lin0b) * dinv -> bufAb
  bgemm_k<2,true,false,true,true><<<nGB, 256, 0, stream>>>(xb, lin0wt, lin0b, nullptr, dinv, nullptr, bufAb, Mn, 0.f);
  // 6) layer 0 fused: gather agg from bufAb + GEMM + resid + dinv-prescale -> bufCb
  agg_bgemm_k<false><<<nGB, 256, 0, stream>>>(bufAb, off, csr_sd, csr_w2, dinv,
                                              cw1t0, nullptr, nullptr, bufCb, nullptr, Mn, beta0);
  // 7) layer 1 fused: gather agg from bufCb + GEMM + resid + final out GEMM
  agg_bgemm_k<true><<<nGB, 256, 0, stream>>>(bufCb, off, csr_sd, csr_w2, dinv,
                                             cw1t1, lin1wt, lin1b, nullptr, out, Mn, beta1);
}

// Round 14
// 360.809 us; speedup vs baseline: 1.0573x; 1.0573x over previous
//
#include <hip/hip_runtime.h>
#include <hip/hip_bf16.h>
#include <hip/hip_fp16.h>
#include <math.h>

#define NN 50000
#define NE 800000

typedef __attribute__((ext_vector_type(8))) short bf16x8;
typedef __attribute__((ext_vector_type(4))) float f32x4;

__device__ __forceinline__ short f2bf(float f){
  unsigned u = __float_as_uint(f);
  unsigned r = (u + 0x7fffu + ((u >> 16) & 1u)) >> 16;
  return (short)r;
}
__device__ __forceinline__ float bf2f(short s){
  return __uint_as_float(((unsigned)(unsigned short)s) << 16);
}

// ---- fp8 e5m2-style via exact f16 scaling (encode keeps top 8 bits of f16) ----
__device__ __forceinline__ unsigned f2fp8(float f){
  __half h = __float2half(f * 0.00390625f);          // v * 2^-8, RNE
  unsigned hb = (unsigned)__half_as_ushort(h);
  unsigned s = hb >> 15;
  unsigned mag = hb & 0x7fffu;
  mag = mag + 0x3fu + ((mag >> 7) & 1u);             // RNE drop of low 7 bits
  unsigned m8 = mag >> 7;
  if (m8 > 0x7eu) m8 = 0x7eu;
  return (s << 7) | m8;
}
__device__ __forceinline__ void fp8x4_dec(unsigned u, float2& lo, float2& hi){
  unsigned l = ((u & 0x80u) << 8) | ((u & 0x7fu) << 7)
             | ((u & 0x8000u) << 16) | ((u & 0x7f00u) << 15);
  unsigned h = ((u & 0x800000u) >> 8) | ((u & 0x7f0000u) >> 9)
             | (u & 0x80000000u) | ((u & 0x7f000000u) >> 1);
  __half2 hl = *(__half2*)&l;
  __half2 hh = *(__half2*)&h;
  lo = __half22float2(hl);
  hi = __half22float2(hh);
}
// manual decode kept deliberately: its VALU work overlaps gather latency (r6 lesson)
__device__ __forceinline__ float fp8_dot4(unsigned a, unsigned b){
  float2 al, ah, bl, bh;
  fp8x4_dec(a, al, ah); fp8x4_dec(b, bl, bh);
  return al.x*bl.x + al.y*bl.y + ah.x*bh.x + ah.y*bh.y;
}

// ---------------- weight prep (transpose + bf16) + cnt/scal zero + W3P fold ----------------
__global__ __launch_bounds__(256) void prep_k(const float* __restrict__ w1,
    const float* __restrict__ w2, const float* __restrict__ w3, const float* __restrict__ pars,
    const float* __restrict__ b3, const float* __restrict__ lin0w, const float* __restrict__ cw1,
    const float* __restrict__ lin1w,
    short* __restrict__ w1t, short* __restrict__ w2t, short* __restrict__ w3t,
    short* __restrict__ w3pt, float* __restrict__ b3P,
    short* __restrict__ lin0wt, short* __restrict__ cw1t0, short* __restrict__ cw1t1,
    short* __restrict__ lin1wt, int* __restrict__ cnt, float* __restrict__ scal){
  int idx = blockIdx.x*256 + threadIdx.x;
  if (idx < NN) cnt[idx] = 0;
  if (idx < 16) scal[idx] = 0.0f;
  if (idx < 65536){
    int n = idx >> 7, k = idx & 127;
    w1t[idx] = f2bf(w1[k*512 + n]);
  } else if (idx < 98304){
    int i = idx - 65536; int n = i >> 9, k = i & 511;
    w2t[i] = f2bf(w2[k*64 + n]);
  } else if (idx < 102400){
    int i = idx - 98304; int n = i >> 6, k = i & 63;
    w3t[i] = f2bf(w3[k*64 + n]);
  } else if (idx < 106496){
    int i = idx - 102400; int c = i >> 6, k = i & 63;
    float s = 0.f;
    for (int j = 0; j < 64; j++)
      s += w3[k*64 + j] * fmaxf(2.f*pars[j*64 + c], 0.f);
    w3pt[i] = f2bf(s);
  } else if (idx < 122880){
    int i = idx - 106496; int n = i >> 7, k = i & 127;
    lin0wt[i] = f2bf(lin0w[k*128 + n]);
  } else if (idx < 139264){
    int i = idx - 122880; int n = i >> 7, k = i & 127;
    cw1t0[i] = f2bf(cw1[k*128 + n]);
  } else if (idx < 155648){
    int i = idx - 139264; int n = i >> 7, k = i & 127;
    cw1t1[i] = f2bf(cw1[16384 + k*128 + n]);
  } else if (idx < 163840){
    int i = idx - 155648; int n = i >> 7, k = i & 127;   // n in [0,64)
    lin1wt[i] = f2bf(lin1w[k*64 + n]);
  } else if (idx < 163904){
    int c = idx - 163840;
    float s = 0.f;
    for (int j = 0; j < 64; j++) s += b3[j] * fmaxf(2.f*pars[j*64 + c], 0.f);
    b3P[c] = s;
  }
}

// ---------------- fused bf16-MFMA MLP chain (64 rows/block, half-split, pad-4) ----------------
__global__ __launch_bounds__(256) void mlp_mfma_k(
    const float* __restrict__ x,
    const short* __restrict__ w1t, const float* __restrict__ b1,
    const short* __restrict__ w2t, const float* __restrict__ b2,
    const short* __restrict__ w3t, const float* __restrict__ b3,
    const short* __restrict__ w3pt, const float* __restrict__ b3P,
    unsigned char* __restrict__ lg8, unsigned char* __restrict__ lgp8,
    short* __restrict__ xb, int M)
{
  __shared__ short xs [64][132];
  __shared__ short h1s[64][260];  // one 256-col half of h1 (+4 pad)
  __shared__ short h2s[64][68];   // phase2 out; overwritten with logitsP after merged phase
  __shared__ short lgs[64][68];
  const int t = threadIdx.x;
  const int wave = t >> 6, lane = t & 63;
  const int quad = lane >> 4, l16 = lane & 15;
  const int m0 = blockIdx.x * 64;

  // stage x -> LDS (bf16), and dump xb directly from registers (fire-and-forget)
  for (int task = t; task < 1024; task += 256){
    int row = task >> 4, c0 = (task & 15) * 8;
    float4 v0 = make_float4(0,0,0,0), v1 = v0;
    int gm = m0 + row;
    if (gm < M){
      v0 = *(const float4*)(x + (size_t)gm*128 + c0);
      v1 = *(const float4*)(x + (size_t)gm*128 + c0 + 4);
    }
    bf16x8 s;
    s[0]=f2bf(v0.x); s[1]=f2bf(v0.y); s[2]=f2bf(v0.z); s[3]=f2bf(v0.w);
    s[4]=f2bf(v1.x); s[5]=f2bf(v1.y); s[6]=f2bf(v1.z); s[7]=f2bf(v1.w);
    *(bf16x8*)&xs[row][c0] = s;
    if (gm < M) *(bf16x8*)(xb + (size_t)gm*128 + c0) = s;
  }
  __syncthreads();

  // ---- Phases 1+2 interleaved over two K-halves of h1 ----
  f32x4 acc2a[4], acc2b[4];
  #pragma unroll
  for (int mt=0;mt<4;mt++){ acc2a[mt] = (f32x4){0.f,0.f,0.f,0.f}; acc2b[mt] = acc2a[mt]; }
  const int n2 = wave*16 + l16;           // phase-2 output column

  #pragma unroll
  for (int half = 0; half < 2; half++){
    // phase 1 (half): h1[:, half*256 .. +256) = relu(x @ w1 + b1), 64 rows
    {
      f32x4 acc[4][4];
      #pragma unroll
      for (int mt=0;mt<4;mt++)
        #pragma unroll
        for (int nt=0;nt<4;nt++) acc[mt][nt] = (f32x4){0.f,0.f,0.f,0.f};
      #pragma unroll
      for (int k0 = 0; k0 < 128; k0 += 32){
        bf16x8 a0 = *(const bf16x8*)&xs[l16     ][k0 + quad*8];
        bf16x8 a1 = *(const bf16x8*)&xs[16 + l16][k0 + quad*8];
        bf16x8 a2 = *(const bf16x8*)&xs[32 + l16][k0 + quad*8];
        bf16x8 a3 = *(const bf16x8*)&xs[48 + l16][k0 + quad*8];
        #pragma unroll
        for (int nt = 0; nt < 4; nt++){
          int n = half*256 + wave*64 + nt*16 + l16;
          bf16x8 b = *(const bf16x8*)(w1t + (size_t)n*128 + k0 + quad*8);
          acc[0][nt] = __builtin_amdgcn_mfma_f32_16x16x32_bf16(a0, b, acc[0][nt], 0,0,0);
          acc[1][nt] = __builtin_amdgcn_mfma_f32_16x16x32_bf16(a1, b, acc[1][nt], 0,0,0);
          acc[2][nt] = __builtin_amdgcn_mfma_f32_16x16x32_bf16(a2, b, acc[2][nt], 0,0,0);
          acc[3][nt] = __builtin_amdgcn_mfma_f32_16x16x32_bf16(a3, b, acc[3][nt], 0,0,0);
        }
      }
      #pragma unroll
      for (int nt = 0; nt < 4; nt++){
        int n  = half*256 + wave*64 + nt*16 + l16;
        int cl = wave*64 + nt*16 + l16;
        float bb = b1[n];
        #pragma unroll
        for (int mt = 0; mt < 4; mt++){
          #pragma unroll
          for (int r = 0; r < 4; r++){
            int row = mt*16 + quad*4 + r;
            h1s[row][cl] = f2bf(fmaxf(acc[mt][nt][r] + bb, 0.f));
          }
        }
      }
    }
    __syncthreads();

    // phase 2 partial: acc2 += h1(half) @ w2[half K range]; 2 indep accs per m-tile
    #pragma unroll
    for (int k0 = 0; k0 < 128; k0 += 32){
      bf16x8 bA = *(const bf16x8*)(w2t + (size_t)n2*512 + half*256 + k0 + quad*8);
      bf16x8 bB = *(const bf16x8*)(w2t + (size_t)n2*512 + half*256 + 128 + k0 + quad*8);
      #pragma unroll
      for (int mt = 0; mt < 4; mt++){
        bf16x8 aA = *(const bf16x8*)&h1s[mt*16 + l16][k0 + quad*8];
        bf16x8 aB = *(const bf16x8*)&h1s[mt*16 + l16][128 + k0 + quad*8];
        acc2a[mt] = __builtin_amdgcn_mfma_f32_16x16x32_bf16(aA, bA, acc2a[mt], 0,0,0);
        acc2b[mt] = __builtin_amdgcn_mfma_f32_16x16x32_bf16(aB, bB, acc2b[mt], 0,0,0);
      }
    }
    if (half == 0) __syncthreads();   // protect h1s before overwrite
  }

  // h2 = relu(acc2a+acc2b + b2) -> h2s
  {
    float bb = b2[n2];
    #pragma unroll
    for (int mt = 0; mt < 4; mt++)
      #pragma unroll
      for (int r = 0; r < 4; r++)
        h2s[mt*16 + quad*4 + r][n2] = f2bf(fmaxf(acc2a[mt][r] + acc2b[mt][r] + bb, 0.f));
  }
  __syncthreads();

  // ---- Merged Phase 3+4: logits = h2@w3t + b3 ; logitsP = h2@w3pt + b3P ----
  {
    f32x4 accL[4], accP[4];
    #pragma unroll
    for (int mt=0;mt<4;mt++){ accL[mt] = (f32x4){0.f,0.f,0.f,0.f}; accP[mt] = accL[mt]; }
    #pragma unroll
    for (int k0 = 0; k0 < 64; k0 += 32){
      bf16x8 bL = *(const bf16x8*)(w3t  + (size_t)n2*64 + k0 + quad*8);
      bf16x8 bP = *(const bf16x8*)(w3pt + (size_t)n2*64 + k0 + quad*8);
      #pragma unroll
      for (int mt = 0; mt < 4; mt++){
        bf16x8 a = *(const bf16x8*)&h2s[mt*16 + l16][k0 + quad*8];
        accL[mt] = __builtin_amdgcn_mfma_f32_16x16x32_bf16(a, bL, accL[mt], 0,0,0);
        accP[mt] = __builtin_amdgcn_mfma_f32_16x16x32_bf16(a, bP, accP[mt], 0,0,0);
      }
    }
    __syncthreads();   // all h2s reads complete before overwrite
    float bbL = b3[n2], bbP = b3P[n2];
    #pragma unroll
    for (int mt = 0; mt < 4; mt++)
      #pragma unroll
      for (int r = 0; r < 4; r++){
        lgs[mt*16 + quad*4 + r][n2] = f2bf(accL[mt][r] + bbL);
        h2s[mt*16 + quad*4 + r][n2] = f2bf(accP[mt][r] + bbP);
      }
  }
  __syncthreads();

  // ---- cooperative store: lgs -> lg8 (fp8), h2s -> lgp8 (fp8); 16 cols/thread ----
  {
    int row = t >> 2, c0 = (t & 3) * 16;
    int gm = m0 + row;
    if (gm < M){
      const short* pl = &lgs[row][c0];
      const short* pp = &h2s[row][c0];
      unsigned a[4] = {0,0,0,0}, b[4] = {0,0,0,0};
      #pragma unroll
      for (int q2 = 0; q2 < 4; q2++){
        #pragma unroll
        for (int j = 0; j < 4; j++){
          a[q2] |= f2fp8(bf2f(pl[q2*4+j])) << (8*j);
          b[q2] |= f2fp8(bf2f(pp[q2*4+j])) << (8*j);
        }
      }
      uint4 av; av.x=a[0]; av.y=a[1]; av.z=a[2]; av.w=a[3];
      uint4 bv; bv.x=b[0]; bv.y=b[1]; bv.z=b[2]; bv.w=b[3];
      *(uint4*)(lg8  + (size_t)gm*64 + c0) = av;
      *(uint4*)(lgp8 + (size_t)gm*64 + c0) = bv;
    }
  }
}

// ---------------- bf16 MFMA GEMM: C[M][N] = EPI(A[M][128] @ Bt[N][128]^T) ----------------
// SCALEROW: multiply output row by dinvp[row] (pre-scales h for the next gather)
template<int NT, bool RELU, bool RESID, bool BF16OUT, bool SCALEROW>
__global__ __launch_bounds__(256) void bgemm_k(
    const short* __restrict__ A, const short* __restrict__ Bt,
    const float* __restrict__ bias, const short* __restrict__ extra,
    const float* __restrict__ dinvp,
    float* __restrict__ C, short* __restrict__ Cb, int M, float beta)
{
  const int N = NT*64;
  __shared__ short As[32][132];
  const int t = threadIdx.x;
  const int wave = t >> 6, lane = t & 63;
  const int quad = lane >> 4, l16 = lane & 15;
  const int m0 = blockIdx.x * 32;

  for (int task = t; task < 512; task += 256){
    int row = task >> 4, c0 = (task & 15) * 8;
    bf16x8 v = {0,0,0,0,0,0,0,0};
    if (m0 + row < M) v = *(const bf16x8*)(A + (size_t)(m0+row)*128 + c0);
    *(bf16x8*)&As[row][c0] = v;
  }
  __syncthreads();

  f32x4 acc[2][NT];
  #pragma unroll
  for (int mt=0;mt<2;mt++)
    #pragma unroll
    for (int nt=0;nt<NT;nt++) acc[mt][nt] = (f32x4){0.f,0.f,0.f,0.f};

  #pragma unroll
  for (int k0 = 0; k0 < 128; k0 += 32){
    bf16x8 a0 = *(const bf16x8*)&As[l16     ][k0 + quad*8];
    bf16x8 a1 = *(const bf16x8*)&As[16 + l16][k0 + quad*8];
    #pragma unroll
    for (int nt = 0; nt < NT; nt++){
      int n = (wave*NT + nt)*16 + l16;
      bf16x8 b = *(const bf16x8*)(Bt + (size_t)n*128 + k0 + quad*8);
      acc[0][nt] = __builtin_amdgcn_mfma_f32_16x16x32_bf16(a0, b, acc[0][nt], 0,0,0);
      acc[1][nt] = __builtin_amdgcn_mfma_f32_16x16x32_bf16(a1, b, acc[1][nt], 0,0,0);
    }
  }

  #pragma unroll
  for (int nt = 0; nt < NT; nt++){
    int n = (wave*NT + nt)*16 + l16;
    float bb = (bias != nullptr) ? bias[n] : 0.f;
    #pragma unroll
    for (int mt = 0; mt < 2; mt++){
      #pragma unroll
      for (int r = 0; r < 4; r++){
        int gm = m0 + mt*16 + quad*4 + r;
        if (gm >= M) continue;
        float v = acc[mt][nt][r];
        if (RESID){
          float ex = bf2f(extra[(size_t)gm*N + n]);
          v = beta*v + (1.f - beta)*ex;
        }
        v += bb;
        if (RELU) v = fmaxf(v, 0.f);
        if (SCALEROW) v *= dinvp[gm];
        if (BF16OUT) Cb[(size_t)gm*N + n] = f2bf(v);
        else         C [(size_t)gm*N + n] = v;
      }
    }
  }
}

// ---------------- fused layer-1 bgemm + final out GEMM ----------------
__global__ __launch_bounds__(256) void bgemm_fuse_k(
    const short* __restrict__ A, const short* __restrict__ Bt,
    const short* __restrict__ extra,
    const short* __restrict__ lin1wt, const float* __restrict__ lin1b,
    float* __restrict__ out, int M, float beta)
{
  __shared__ short As[32][132];
  const int t = threadIdx.x;
  const int wave = t >> 6, lane = t & 63;
  const int quad = lane >> 4, l16 = lane & 15;
  const int m0 = blockIdx.x * 32;

  for (int task = t; task < 512; task += 256){
    int row = task >> 4, c0 = (task & 15) * 8;
    bf16x8 v = {0,0,0,0,0,0,0,0};
    if (m0 + row < M) v = *(const bf16x8*)(A + (size_t)(m0+row)*128 + c0);
    *(bf16x8*)&As[row][c0] = v;
  }
  __syncthreads();

  f32x4 acc[2][2];
  #pragma unroll
  for (int mt=0;mt<2;mt++)
    #pragma unroll
    for (int nt=0;nt<2;nt++) acc[mt][nt] = (f32x4){0.f,0.f,0.f,0.f};

  #pragma unroll
  for (int k0 = 0; k0 < 128; k0 += 32){
    bf16x8 a0 = *(const bf16x8*)&As[l16     ][k0 + quad*8];
    bf16x8 a1 = *(const bf16x8*)&As[16 + l16][k0 + quad*8];
    #pragma unroll
    for (int nt = 0; nt < 2; nt++){
      int n = (wave*2 + nt)*16 + l16;
      bf16x8 b = *(const bf16x8*)(Bt + (size_t)n*128 + k0 + quad*8);
      acc[0][nt] = __builtin_amdgcn_mfma_f32_16x16x32_bf16(a0, b, acc[0][nt], 0,0,0);
      acc[1][nt] = __builtin_amdgcn_mfma_f32_16x16x32_bf16(a1, b, acc[1][nt], 0,0,0);
    }
  }
  __syncthreads();   // all As reads done; safe to overwrite with h

  // epilogue: h = relu(beta*acc + (1-beta)*extra), bf16, into As[row][n]
  #pragma unroll
  for (int nt = 0; nt < 2; nt++){
    int n = (wave*2 + nt)*16 + l16;
    #pragma unroll
    for (int mt = 0; mt < 2; mt++){
      #pragma unroll
      for (int r = 0; r < 4; r++){
        int row = mt*16 + quad*4 + r;
        int gm = m0 + row;
        float v = 0.f;
        if (gm < M){
          float ex = bf2f(extra[(size_t)gm*128 + n]);
          v = fmaxf(beta*acc[mt][nt][r] + (1.f - beta)*ex, 0.f);
        }
        As[row][n] = f2bf(v);
      }
    }
  }
  __syncthreads();

  // second GEMM: out[32 x 64] = As(32x128) @ lin1wt(64 x 128 n-major)^T + lin1b
  f32x4 acc2[2];
  acc2[0] = (f32x4){0.f,0.f,0.f,0.f}; acc2[1] = acc2[0];
  const int n2 = wave*16 + l16;     // 4 waves x 16 = 64 output cols
  #pragma unroll
  for (int k0 = 0; k0 < 128; k0 += 32){
    bf16x8 b  = *(const bf16x8*)(lin1wt + (size_t)n2*128 + k0 + quad*8);
    bf16x8 a0 = *(const bf16x8*)&As[l16     ][k0 + quad*8];
    bf16x8 a1 = *(const bf16x8*)&As[16 + l16][k0 + quad*8];
    acc2[0] = __builtin_amdgcn_mfma_f32_16x16x32_bf16(a0, b, acc2[0], 0,0,0);
    acc2[1] = __builtin_amdgcn_mfma_f32_16x16x32_bf16(a1, b, acc2[1], 0,0,0);
  }
  float bb = lin1b[n2];
  #pragma unroll
  for (int mt = 0; mt < 2; mt++)
    #pragma unroll
    for (int r = 0; r < 4; r++){
      int gm = m0 + mt*16 + quad*4 + r;
      if (gm < M) out[(size_t)gm*64 + n2] = acc2[mt][r] + bb;
    }
}

// ---------------- count in-degree + record per-edge rank (4 edges/thread ILP) ----------------
__global__ __launch_bounds__(256) void count_k(const int* __restrict__ col, int* __restrict__ cnt,
    int* __restrict__ rank, int E){
  int i = (blockIdx.x*256 + threadIdx.x)*4;
  if (i + 3 < E){
    int4 c = *(const int4*)(col + i);
    int r0 = atomicAdd(&cnt[c.x], 1);
    int r1 = atomicAdd(&cnt[c.y], 1);
    int r2 = atomicAdd(&cnt[c.z], 1);
    int r3 = atomicAdd(&cnt[c.w], 1);
    *(int4*)(rank + i) = make_int4(r0, r1, r2, r3);
  } else {
    for (; i < E; i++) rank[i] = atomicAdd(&cnt[col[i]], 1);
  }
}

// ---------------- scan: per-block sums, then final (block base summed in-kernel) ----------------
__global__ __launch_bounds__(256) void scan_sums_k(const int* __restrict__ cnt, int* __restrict__ bsum, int n){
  __shared__ int s[256];
  const int t = threadIdx.x;
  int i = blockIdx.x*1024 + t*4;
  int4 v = make_int4(0,0,0,0);
  if (i + 3 < n) v = *(const int4*)(cnt + i);
  else {
    if (i   < n) v.x = cnt[i];
    if (i+1 < n) v.y = cnt[i+1];
    if (i+2 < n) v.z = cnt[i+2];
    if (i+3 < n) v.w = cnt[i+3];
  }
  s[t] = v.x + v.y + v.z + v.w;
  __syncthreads();
  for (int st = 128; st; st >>= 1){
    if (t < st) s[t] += s[t + st];
    __syncthreads();
  }
  if (t == 0) bsum[blockIdx.x] = s[0];
}

__global__ __launch_bounds__(256) void scan_final_k(const int* __restrict__ cnt, const int* __restrict__ bsum,
    int* __restrict__ off, int n, int total, int nb){
  __shared__ int s[256];
  __shared__ int basebs;
  const int t = threadIdx.x;
  if (t < 64){
    int v = (t < nb && t < (int)blockIdx.x) ? bsum[t] : 0;
    #pragma unroll
    for (int o = 1; o < 64; o <<= 1) v += __shfl_xor(v, o);
    if (t == 0) basebs = v;
  }
  int i = blockIdx.x*1024 + t*4;
  int4 v = make_int4(0,0,0,0);
  if (i + 3 < n) v = *(const int4*)(cnt + i);
  else {
    if (i   < n) v.x = cnt[i];
    if (i+1 < n) v.y = cnt[i+1];
    if (i+2 < n) v.z = cnt[i+2];
    if (i+3 < n) v.w = cnt[i+3];
  }
  int tsum = v.x + v.y + v.z + v.w;
  s[t] = tsum;
  __syncthreads();
  #pragma unroll
  for (int st = 1; st < 256; st <<= 1){
    int a = (t >= st) ? s[t - st] : 0;
    __syncthreads();
    s[t] += a;
    __syncthreads();
  }
  int base = s[t] - tsum + basebs;
  int o0 = base, o1 = o0 + v.x, o2 = o1 + v.y, o3 = o2 + v.z;
  if (i   < n) off[i]   = o0;
  if (i+1 < n) off[i+1] = o1;
  if (i+2 < n) off[i+2] = o2;
  if (i+3 < n) off[i+3] = o3;
  if (blockIdx.x == 0 && t == 0) off[n] = total;
}

// bucket edges by destination; slot = off[c] + rank[e] (NO atomic; 4 edges/thread ILP)
__global__ __launch_bounds__(256) void scatter_k(const int* __restrict__ row, const int* __restrict__ col,
    const int* __restrict__ off, const int* __restrict__ rank,
    int2* __restrict__ csr_sd, int E){
  int i = (blockIdx.x*256 + threadIdx.x)*4;
  if (i + 3 < E){
    int4 r = *(const int4*)(row + i);
    int4 c = *(const int4*)(col + i);
    int4 k = *(const int4*)(rank + i);
    int o0 = off[c.x], o1 = off[c.y], o2 = off[c.z], o3 = off[c.w];
    int2 p0; p0.x = r.x; p0.y = c.x;
    int2 p1; p1.x = r.y; p1.y = c.y;
    int2 p2; p2.x = r.z; p2.y = c.z;
    int2 p3; p3.x = r.w; p3.y = c.w;
    csr_sd[o0 + k.x] = p0;
    csr_sd[o1 + k.y] = p1;
    csr_sd[o2 + k.z] = p2;
    csr_sd[o3 + k.w] = p3;
  } else {
    for (; i < E; i++){
      int2 p; p.x = row[i]; p.y = col[i];
      csr_sd[off[col[i]] + rank[i]] = p;
    }
  }
}

// ---------------- ew over CSR slots: 16-lane groups, 8-edge batch pipeline ----------------
__global__ __launch_bounds__(256) void ew2_k(const unsigned char* __restrict__ lg8,
    const unsigned char* __restrict__ lgp8,
    const int2* __restrict__ sd,
    float* __restrict__ w, float* __restrict__ scal, int E){
  const int t = threadIdx.x;
  const int lane = t & 63, wid = t >> 6;
  const int g = lane >> 4, q = lane & 15;
  const int gid = (blockIdx.x*4 + wid)*4 + g;     // global 16-lane group id
  const int ngroups = gridDim.x*16;
  float s = 0.f, ss = 0.f;
  for (int base = gid*8; base < E; base += ngroups*8){   // E % 8 == 0
    int4 p01 = *(const int4*)(sd + base);
    int4 p23 = *(const int4*)(sd + base + 2);
    int4 p45 = *(const int4*)(sd + base + 4);
    int4 p67 = *(const int4*)(sd + base + 6);
    unsigned a0 = *(const unsigned*)(lg8  + (size_t)p01.x*64 + q*4);
    unsigned a1 = *(const unsigned*)(lg8  + (size_t)p01.z*64 + q*4);
    unsigned a2 = *(const unsigned*)(lg8  + (size_t)p23.x*64 + q*4);
    unsigned a3 = *(const unsigned*)(lg8  + (size_t)p23.z*64 + q*4);
    unsigned a4 = *(const unsigned*)(lg8  + (size_t)p45.x*64 + q*4);
    unsigned a5 = *(const unsigned*)(lg8  + (size_t)p45.z*64 + q*4);
    unsigned a6 = *(const unsigned*)(lg8  + (size_t)p67.x*64 + q*4);
    unsigned a7 = *(const unsigned*)(lg8  + (size_t)p67.z*64 + q*4);
    unsigned b0 = *(const unsigned*)(lgp8 + (size_t)p01.y*64 + q*4);
    unsigned b1 = *(const unsigned*)(lgp8 + (size_t)p01.w*64 + q*4);
    unsigned b2 = *(const unsigned*)(lgp8 + (size_t)p23.y*64 + q*4);
    unsigned b3 = *(const unsigned*)(lgp8 + (size_t)p23.w*64 + q*4);
    unsigned b4 = *(const unsigned*)(lgp8 + (size_t)p45.y*64 + q*4);
    unsigned b5 = *(const unsigned*)(lgp8 + (size_t)p45.w*64 + q*4);
    unsigned b6 = *(const unsigned*)(lgp8 + (size_t)p67.y*64 + q*4);
    unsigned b7 = *(const unsigned*)(lgp8 + (size_t)p67.w*64 + q*4);
    float v0 = fp8_dot4(a0, b0);
    float v1 = fp8_dot4(a1, b1);
    float v2 = fp8_dot4(a2, b2);
    float v3 = fp8_dot4(a3, b3);
    float v4 = fp8_dot4(a4, b4);
    float v5 = fp8_dot4(a5, b5);
    float v6 = fp8_dot4(a6, b6);
    float v7 = fp8_dot4(a7, b7);
    #pragma unroll
    for (int o = 1; o < 16; o <<= 1){
      v0 += __shfl_xor(v0, o); v1 += __shfl_xor(v1, o);
      v2 += __shfl_xor(v2, o); v3 += __shfl_xor(v3, o);
      v4 += __shfl_xor(v4, o); v5 += __shfl_xor(v5, o);
      v6 += __shfl_xor(v6, o); v7 += __shfl_xor(v7, o);
    }
    if (q == 0){
      float4 va = make_float4(v0*65536.f, v1*65536.f, v2*65536.f, v3*65536.f);
      float4 vb = make_float4(v4*65536.f, v5*65536.f, v6*65536.f, v7*65536.f);
      *(float4*)(w + base)     = va;
      *(float4*)(w + base + 4) = vb;
      s  += va.x + va.y + va.z + va.w + vb.x + vb.y + vb.z + vb.w;
      ss += va.x*va.x + va.y*va.y + va.z*va.z + va.w*va.w
          + vb.x*vb.x + vb.y*vb.y + vb.z*vb.z + vb.w*vb.w;
    }
  }
  #pragma unroll
  for (int o = 1; o < 64; o <<= 1){ s += __shfl_xor(s, o); ss += __shfl_xor(ss, o); }
  __shared__ float ls[4], lss[4];
  if (lane == 0){ ls[wid] = s; lss[wid] = ss; }
  __syncthreads();
  if (t == 0){
    atomicAdd(&scal[0], ls[0]+ls[1]+ls[2]+ls[3]);
    atomicAdd(&scal[1], lss[0]+lss[1]+lss[2]+lss[3]);
  }
}

// normalize bucket in place (stats inline), deg = 1 + sum(w), dinv = rsqrt(deg)
__global__ __launch_bounds__(256) void degnorm_k(float* __restrict__ w, const int* __restrict__ off,
    const float* __restrict__ scal, float* __restrict__ dinv, int Nn, int E){
  int n = blockIdx.x*256 + threadIdx.x;
  if (n < Nn){
    double sum = (double)scal[0], sumsq = (double)scal[1];
    double mean_d = sum / (double)E;
    double var    = (sumsq - sum*sum/(double)E) / (double)(E-1);
    float mean = (float)mean_d;
    float k    = (float)sqrt(1e-4 / var);
    int s = off[n], e = off[n+1];
    float d = 1.0f;
    for (int j = s; j < e; j++){
      float v = (w[j] - mean) * k + 1.0f;
      w[j] = v;
      d += v;
    }
    dinv[n] = (d > 0.f) ? rsqrtf(d) : 0.f;
  }
}

// CSR gather aggregation from dinv-prescaled bf16 h': agg[n] = dinv[n]*(h'[n] + sum w*h'[src])
// ONE WAVE PER NODE (r13 lesson: gather node-parallelism is sacred)
__global__ __launch_bounds__(256) void agg_gather_k(const short* __restrict__ hb,
    const int* __restrict__ off, const int2* __restrict__ sd, const float* __restrict__ w,
    const float* __restrict__ dinv, short* __restrict__ aggb, int Nn){
  int n = blockIdx.x*4 + (threadIdx.x >> 6);
  int lane = threadIdx.x & 63;
  if (n >= Nn) return;
  float d = dinv[n];
  short2 hv = *(const short2*)(hb + (size_t)n*128 + lane*2);
  float acc0 = bf2f(hv.x), acc1 = bf2f(hv.y);    // self term: h'[n] (already dinv-scaled)
  int s = off[n], e = off[n+1];
  int j = s;
  for (; j + 7 < e; j += 8){
    int4 p0 = *(const int4*)(sd + j);
    int4 p1 = *(const int4*)(sd + j + 2);
    int4 p2 = *(const int4*)(sd + j + 4);
    int4 p3 = *(const int4*)(sd + j + 6);
    float4 w0 = *(const float4*)(w + j);
    float4 w1 = *(const float4*)(w + j + 4);
    short2 h0 = *(const short2*)(hb + (size_t)p0.x*128 + lane*2);
    short2 h1 = *(const short2*)(hb + (size_t)p0.z*128 + lane*2);
    short2 h2 = *(const short2*)(hb + (size_t)p1.x*128 + lane*2);
    short2 h3 = *(const short2*)(hb + (size_t)p1.z*128 + lane*2);
    short2 h4 = *(const short2*)(hb + (size_t)p2.x*128 + lane*2);
    short2 h5 = *(const short2*)(hb + (size_t)p2.z*128 + lane*2);
    short2 h6 = *(const short2*)(hb + (size_t)p3.x*128 + lane*2);
    short2 h7 = *(const short2*)(hb + (size_t)p3.z*128 + lane*2);
    acc0 += w0.x*bf2f(h0.x) + w0.y*bf2f(h1.x) + w0.z*bf2f(h2.x) + w0.w*bf2f(h3.x)
          + w1.x*bf2f(h4.x) + w1.y*bf2f(h5.x) + w1.z*bf2f(h6.x) + w1.w*bf2f(h7.x);
    acc1 += w0.x*bf2f(h0.y) + w0.y*bf2f(h1.y) + w0.z*bf2f(h2.y) + w0.w*bf2f(h3.y)
          + w1.x*bf2f(h4.y) + w1.y*bf2f(h5.y) + w1.z*bf2f(h6.y) + w1.w*bf2f(h7.y);
  }
  for (; j < e; j++){
    int2 p = sd[j];
    short2 h0 = *(const short2*)(hb + (size_t)p.x*128 + lane*2);
    float w0 = w[j];
    acc0 += w0*bf2f(h0.x); acc1 += w0*bf2f(h0.y);
  }
  acc0 *= d; acc1 *= d;
  short2 o; o.x = f2bf(acc0); o.y = f2bf(acc1);
  *(short2*)(aggb + (size_t)n*128 + lane*2) = o;
}

extern "C" void kernel_launch(void* const* d_in, const int* in_sizes, int n_in,
                              void* d_out, int out_size, void* d_ws, size_t ws_size,
                              hipStream_t stream){
  const float* x      = (const float*)d_in[0];
  const int*   ei     = (const int*)  d_in[1];
  const float* w1     = (const float*)d_in[2];
  const float* b1     = (const float*)d_in[3];
  const float* w2     = (const float*)d_in[4];
  const float* b2     = (const float*)d_in[5];
  const float* w3     = (const float*)d_in[6];
  const float* b3     = (const float*)d_in[7];
  const float* pars   = (const float*)d_in[8];
  const float* lin0w  = (const float*)d_in[9];
  const float* lin0b  = (const float*)d_in[10];
  const float* lin1w  = (const float*)d_in[11];
  const float* lin1b  = (const float*)d_in[12];
  const float* cw1    = (const float*)d_in[13];
  float* out          = (float*)d_out;

  float* ws = (float*)d_ws;
  // workspace layout (float-element offsets)
  int*   cnt     = (int*)(ws + 0);            //    50,000
  int*   off     = (int*)(ws + 50048);        //    50,001
  int2*  csr_sd  = (int2*)(ws + 150144);      //   800,000 int2 (1.6M ints, ends 1,750,144)
  int*   bsum    = (int*)(ws + 1750400);      //        64
  short* lin0wt  = (short*)(ws + 1751000);    //  16,384 shorts
  short* cw1t0   = lin0wt + 16384;            //  16,384
  short* cw1t1   = cw1t0 + 16384;             //  16,384
  short* lin1wt  = cw1t1 + 16384;             //   8,192
  unsigned char* lg8  = (unsigned char*)(ws + 1800000);  // 3.2M bytes (fp8 logits)
  unsigned char* lgp8 = (unsigned char*)(ws + 2600000);  // 3.2M bytes (fp8 logitsP)
  float* csr_w2  = ws + 3400000;              //   800,000 floats (raw ew -> normalized)
  float* dinv    = ws + 5800000;              //    50,000
  float* scal    = ws + 5850048;              //        16 (ends 5850064)
  float* b3P     = ws + 5850064;              //        64 (ends 5850128)
  short* bufAb   = (short*)(ws + 5900000);    // 6.4M shorts (x0 * dinv)
  short* bufCb   = (short*)(ws + 9100000);    // 6.4M shorts (h after layer0 * dinv)
  short* aggb    = (short*)(ws + 12300000);   // 6.4M shorts (aggregation out)
  short* w1t     = (short*)(ws + 18700000);   // 106,496 shorts MLP weights
  short* w2t     = w1t + 65536;
  short* w3t     = w2t + 32768;
  short* w3pt    = w3t + 4096;                // 4,096 shorts (W3P = w3 @ relu(2P))
  short* xb      = (short*)(ws + 18800000);   // 6.4M shorts (bf16 x, ends 22,000,000)
  int*   rank    = (int*)(ws + 22000000);     //   800,000 ints (ends 22,800,000)

  const int Mn = NN, E = NE;
  const int* erow = ei;
  const int* ecol = ei + E;
  const float beta0 = 0.69314718055994530942f;  // ln(2)
  const float beta1 = 0.40546510810816438198f;  // ln(1.5)
  const int nScanB = (Mn + 1023) / 1024;        // 49 <= 64
  const int nGB = (Mn + 31) / 32;               // bgemm grid
  const int nE4 = (E/4 + 255) / 256;            // 4-edges-per-thread grids

  // 1) weight prep + cnt/scal zero + W3P/b3P fold (fused)
  prep_k<<<(163904+255)/256, 256, 0, stream>>>(w1, w2, w3, pars, b3, lin0w, cw1, lin1w,
                                               w1t, w2t, w3t, w3pt, b3P,
                                               lin0wt, cw1t0, cw1t1, lin1wt, cnt, scal);
  // 2) CSR structure: count (records rank) + scan (2 kernels) + atomic-free scatter
  count_k<<<nE4, 256, 0, stream>>>(ecol, cnt, rank, E);
  scan_sums_k<<<nScanB, 256, 0, stream>>>(cnt, bsum, Mn);
  scan_final_k<<<nScanB, 256, 0, stream>>>(cnt, bsum, off, Mn, E, nScanB);
  scatter_k<<<nE4, 256, 0, stream>>>(erow, ecol, off, rank, csr_sd, E);
  // 3) fused bf16-MFMA MLP chain (merged P3/P4 via W3P) -> lg8, lgp8 + xb
  mlp_mfma_k<<<(Mn+63)/64, 256, 0, stream>>>(x, w1t, b1, w2t, b2, w3t, b3, w3pt, b3P,
                                             lg8, lgp8, xb, Mn);
  // 4) ew (manual decode, 8-edge batch, 1024 blocks) + stats; degnorm -> w + dinv
  ew2_k<<<1024, 256, 0, stream>>>(lg8, lgp8, csr_sd, csr_w2, scal, E);
  degnorm_k<<<(Mn+255)/256, 256, 0, stream>>>(csr_w2, off, scal, dinv, Mn, E);
  // 5) x0' = relu(xb@lin0wt + lin0b) * dinv -> bufAb
  bgemm_k<2,true,false,true,true><<<nGB, 256, 0, stream>>>(xb, lin0wt, lin0b, nullptr, dinv, nullptr, bufAb, Mn, 0.f);
  // 6) layer 0: gather agg (wave-per-node) from bufAb; h' -> bufCb (prescaled)
  agg_gather_k<<<(Mn+3)/4, 256, 0, stream>>>(bufAb, off, csr_sd, csr_w2, dinv, aggb, Mn);
  bgemm_k<2,true,true,true,true><<<nGB, 256, 0, stream>>>(aggb, cw1t0, nullptr, aggb, dinv, nullptr, bufCb, Mn, beta0);
  // 7) layer 1: gather agg from bufCb; fused h + final out GEMM
  agg_gather_k<<<(Mn+3)/4, 256, 0, stream>>>(bufCb, off, csr_sd, csr_w2, dinv, aggb, Mn);
  bgemm_fuse_k<<<nGB, 256, 0, stream>>>(aggb, cw1t1, aggb, lin1wt, lin1b, out, Mn, beta1);
}